// Round 6
// baseline (375.349 us; speedup 1.0000x reference)
//
#include <hip/hip_runtime.h>

// LIF neuron forward scan: x [B,N,T] f32, T=256 contiguous (last axis).
// u = u*TAU + x_t; s = (u >= VTH); u = s ? 0 : u; emit s.
// TAU=0.125 (2^-3) -> u*TAU exact -> recurrence bit-matches numpy ref.
//
// R6 changes vs R5 baseline (61.7us, WRITE 187MB/134MB ideal, FETCH 66MB):
//  - nontemporal stores: output is write-once -> don't allocate in L1/L2/L3.
//    Keeps 128MiB input L3-resident (input+output no longer fight for 256MiB)
//    and kills partial-line write-allocate churn (the 1.39x over-write).
//  - 64B (4x float4) per iteration + unroll 4 -> ~16 loads in flight/thread
//    (VGPR was 24 -> only ~2 in flight) to cover latency at 2 waves/SIMD.

typedef float f32x4 __attribute__((ext_vector_type(4)));

constexpr int   T   = 256;
constexpr int   TV  = T / 4;     // 64 float4 per sequence
constexpr float TAU = 0.125f;
constexpr float VTH = 1.0f;

__global__ __launch_bounds__(256)
void lif_fwd(const f32x4* __restrict__ x, f32x4* __restrict__ out, int nseq) {
    int seq = blockIdx.x * blockDim.x + threadIdx.x;
    if (seq >= nseq) return;

    const f32x4* xp = x   + (size_t)seq * TV;
    f32x4*       op = out + (size_t)seq * TV;

    float u = 0.0f;
#define STEP(vv, ss) { u = u * TAU + (vv); bool b = (u >= VTH); (ss) = b ? 1.0f : 0.0f; u = b ? 0.0f : u; }
#pragma unroll 4
    for (int c = 0; c < TV; c += 4) {
        f32x4 v0 = xp[c + 0];
        f32x4 v1 = xp[c + 1];
        f32x4 v2 = xp[c + 2];
        f32x4 v3 = xp[c + 3];
        f32x4 s0, s1, s2, s3;
        STEP(v0.x, s0.x) STEP(v0.y, s0.y) STEP(v0.z, s0.z) STEP(v0.w, s0.w)
        STEP(v1.x, s1.x) STEP(v1.y, s1.y) STEP(v1.z, s1.z) STEP(v1.w, s1.w)
        STEP(v2.x, s2.x) STEP(v2.y, s2.y) STEP(v2.z, s2.z) STEP(v2.w, s2.w)
        STEP(v3.x, s3.x) STEP(v3.y, s3.y) STEP(v3.z, s3.z) STEP(v3.w, s3.w)
        __builtin_nontemporal_store(s0, &op[c + 0]);
        __builtin_nontemporal_store(s1, &op[c + 1]);
        __builtin_nontemporal_store(s2, &op[c + 2]);
        __builtin_nontemporal_store(s3, &op[c + 3]);
    }
#undef STEP
}

extern "C" void kernel_launch(void* const* d_in, const int* in_sizes, int n_in,
                              void* d_out, int out_size, void* d_ws, size_t ws_size,
                              hipStream_t stream) {
    const float* x = (const float*)d_in[0];
    float* out = (float*)d_out;

    int nseq = in_sizes[0] / T;          // 32*4096 = 131072 sequences
    int block = 256;
    int grid  = (nseq + block - 1) / block;

    lif_fwd<<<grid, block, 0, stream>>>(
        (const f32x4*)x, (f32x4*)out, nseq);
}

// Round 7
// 46.040 us; speedup vs baseline: 8.1527x; 8.1527x over previous
//
#include <hip/hip_runtime.h>

// LIF neuron forward scan: x [B,N,T] f32, T=256 contiguous (last axis).
// u = u*TAU + x_t; s = (u >= VTH); u = s ? 0 : u; emit s.
// TAU=0.125 (2^-3) -> u*TAU exact -> recurrence bit-matches numpy ref.
//
// R7 design (vs R5 flat 61.7us, WRITE 187MB=1.39x, latency-bound ~4.1TB/s):
//  - R6 post-mortem: NT stores bypassed L2 write-combining -> partial-granule
//    HBM writes -> 375us. REVERTED. Scattered 16B stores NEED L2 merging.
//  - This round: LDS-staged phases. Cooperative load (contiguous 128B/seq
//    segments, 8 dwordx4 in flight/thread), per-thread scan on own LDS row
//    (+1-float pad -> 2-way banks = free), cooperative full-line store.
//    2 blocks/CU overlap phases. Targets both write merging and latency.

typedef float f32x4 __attribute__((ext_vector_type(4)));

constexpr int   T    = 256;
constexpr int   TV   = T / 4;     // 64 float4 per row
constexpr int   CT   = 32;        // timesteps per chunk
constexpr int   CV   = CT / 4;    // 8 float4 per row-chunk
constexpr int   NCH  = T / CT;    // 8 chunks
constexpr int   SEQB = 256;       // sequences per block (= blockDim.x)
constexpr int   RP   = CT + 1;    // padded LDS row stride (floats): banks (tid+t)%32
constexpr float TAU  = 0.125f;
constexpr float VTH  = 1.0f;

__global__ __launch_bounds__(256)
void lif_fwd(const f32x4* __restrict__ x, f32x4* __restrict__ out, int nseq) {
    __shared__ float lds[SEQB * RP];       // 256*33*4 = 33.8 KB -> 2+ blocks/CU

    const int tid  = threadIdx.x;
    const int bseq = blockIdx.x * SEQB;    // first sequence of this block

    float u = 0.0f;                        // own sequence's membrane potential

    for (int ch = 0; ch < NCH; ++ch) {
        const size_t cbase = (size_t)bseq * TV + ch * CV;

        // ---- cooperative coalesced load: lanes j*8..j*8+7 cover one seq's 128B ----
        #pragma unroll
        for (int j = 0; j < CV; ++j) {
            int f = j * SEQB + tid;        // 0..2047
            int s = f >> 3;                // f / CV : seq within block
            int k = f & 7;                 // f % CV : float4 within row-chunk
            f32x4 v = x[cbase + (size_t)s * TV + k - (size_t)0 * TV];
            // NOTE: address = (bseq+s)*TV + ch*CV + k
            float* d = &lds[s * RP + k * 4];
            d[0] = v.x; d[1] = v.y; d[2] = v.z; d[3] = v.w;
        }
        __syncthreads();

        // ---- sequential scan on own row (in-place: spike overwrites input) ----
        #pragma unroll
        for (int t = 0; t < CT; ++t) {
            float xv = lds[tid * RP + t];
            u = u * TAU + xv;
            bool b = (u >= VTH);
            lds[tid * RP + t] = b ? 1.0f : 0.0f;
            u = b ? 0.0f : u;
        }
        __syncthreads();

        // ---- cooperative coalesced store (full 64B lines per segment) ----
        #pragma unroll
        for (int j = 0; j < CV; ++j) {
            int f = j * SEQB + tid;
            int s = f >> 3;
            int k = f & 7;
            const float* p = &lds[s * RP + k * 4];
            f32x4 v; v.x = p[0]; v.y = p[1]; v.z = p[2]; v.w = p[3];
            out[cbase + (size_t)s * TV + k] = v;
        }
        __syncthreads();                   // protect LDS before next chunk's load
    }
}

extern "C" void kernel_launch(void* const* d_in, const int* in_sizes, int n_in,
                              void* d_out, int out_size, void* d_ws, size_t ws_size,
                              hipStream_t stream) {
    const float* x = (const float*)d_in[0];
    float* out = (float*)d_out;

    int nseq = in_sizes[0] / T;            // 32*4096 = 131072 sequences
    int grid = nseq / SEQB;                // 512 blocks, exact

    lif_fwd<<<grid, SEQB, 0, stream>>>(
        (const f32x4*)x, (f32x4*)out, nseq);
}

// Round 8
// 44.736 us; speedup vs baseline: 8.3902x; 1.0291x over previous
//
#include <hip/hip_runtime.h>

// LIF neuron forward scan: x [B,N,T] f32, T=256 contiguous (last axis).
// u = u*TAU + x_t; s = (u >= VTH); u = s ? 0 : u; emit s.
// TAU=0.125 (2^-3) -> u*TAU exact -> recurrence bit-matches numpy ref.
//
// R8 design (vs R7: 46.0us, WRITE=128MiB ideal, FETCH=64MiB, eff ~4.4TB/s):
//  - 1-wave (64-thread) blocks: 2048 blocks -> 8 independent pipelines/CU
//    (was 2), and single-wave __syncthreads is near-free.
//  - Double-buffered LDS + register prefetch of chunk c+1 issued BEFORE the
//    scan of chunk c: HBM latency hides under scan+store (T14 async-stage).
//  - Bank layout unchanged (RP=33): scan = (tid+t)%32 -> 2-way = free.

typedef float f32x4 __attribute__((ext_vector_type(4)));

constexpr int   T    = 256;
constexpr int   TV   = T / 4;     // 64 float4 per row
constexpr int   CT   = 32;        // timesteps per chunk
constexpr int   CV   = CT / 4;    // 8 float4 per row-chunk
constexpr int   NCH  = T / CT;    // 8 chunks
constexpr int   SEQB = 64;        // sequences per block (= 1 wave)
constexpr int   RP   = CT + 1;    // padded LDS row stride (floats)
constexpr float TAU  = 0.125f;
constexpr float VTH  = 1.0f;

__global__ __launch_bounds__(64)
void lif_fwd(const f32x4* __restrict__ x, f32x4* __restrict__ out, int nseq) {
    __shared__ float lds[2 * SEQB * RP];   // 2 * 8448 B = 16.9 KB
    float* bufA = lds;                     // scan/store buffer
    float* bufB = lds + SEQB * RP;         // prefetch-landing buffer

    const int tid  = threadIdx.x;          // 0..63
    const int srow = tid >> 3;             // 0..7 : seq-subrow in coop phases
    const int k    = tid & 7;              // 0..7 : float4 within row-chunk
    const int bseq = blockIdx.x * SEQB;

    // ---- prologue: chunk 0 -> bufA (coalesced: 8 seqs x 128B per j) ----
    #pragma unroll
    for (int j = 0; j < CV; ++j) {
        f32x4 v = x[(size_t)(bseq + j*8 + srow) * TV + k];
        float* d = &bufA[(j*8 + srow) * RP + k*4];
        d[0]=v.x; d[1]=v.y; d[2]=v.z; d[3]=v.w;
    }
    __syncthreads();

    float u = 0.0f;
    #pragma unroll
    for (int ch = 0; ch < NCH; ++ch) {
        // ---- issue prefetch of chunk ch+1 into registers (in flight over scan) ----
        f32x4 r[CV];
        if (ch + 1 < NCH) {
            #pragma unroll
            for (int j = 0; j < CV; ++j)
                r[j] = x[(size_t)(bseq + j*8 + srow) * TV + (ch+1)*CV + k];
        }

        // ---- sequential scan of own row, in place (spike overwrites input) ----
        #pragma unroll
        for (int t = 0; t < CT; ++t) {
            float xv = bufA[tid * RP + t];
            u = u * TAU + xv;
            bool b = (u >= VTH);
            bufA[tid * RP + t] = b ? 1.0f : 0.0f;
            u = b ? 0.0f : u;
        }
        __syncthreads();   // single-wave barrier: cheap; orders scan vs coop store

        // ---- cooperative coalesced store of chunk ch from bufA ----
        #pragma unroll
        for (int j = 0; j < CV; ++j) {
            const float* p = &bufA[(j*8 + srow) * RP + k*4];
            f32x4 v; v.x=p[0]; v.y=p[1]; v.z=p[2]; v.w=p[3];
            out[(size_t)(bseq + j*8 + srow) * TV + ch*CV + k] = v;
        }
        // ---- land prefetch regs into bufB ----
        if (ch + 1 < NCH) {
            #pragma unroll
            for (int j = 0; j < CV; ++j) {
                float* d = &bufB[(j*8 + srow) * RP + k*4];
                f32x4 v = r[j];
                d[0]=v.x; d[1]=v.y; d[2]=v.z; d[3]=v.w;
            }
        }
        __syncthreads();

        float* tmp = bufA; bufA = bufB; bufB = tmp;  // unrolled -> compile-time
    }
}

extern "C" void kernel_launch(void* const* d_in, const int* in_sizes, int n_in,
                              void* d_out, int out_size, void* d_ws, size_t ws_size,
                              hipStream_t stream) {
    const float* x = (const float*)d_in[0];
    float* out = (float*)d_out;

    int nseq = in_sizes[0] / T;            // 131072 sequences
    int grid = nseq / SEQB;                // 2048 blocks, exact

    lif_fwd<<<grid, SEQB, 0, stream>>>(
        (const f32x4*)x, (f32x4*)out, nseq);
}